// Round 3
// baseline (284.299 us; speedup 1.0000x reference)
//
#include <hip/hip_runtime.h>
#include <hip/hip_bf16.h>
#include <stdint.h>

typedef __bf16 bf16_t;
typedef bf16_t bf16x8 __attribute__((ext_vector_type(8)));
typedef float f32x4 __attribute__((ext_vector_type(4)));

#define D_IN 64
#define D_OUT 64
#define BM 128
#define NTHREADS 512

// Async global->LDS, 16 B per lane. LDS dest is wave-uniform base; HW writes
// lane i at base + i*16.
#define GLOAD_LDS16(gsrc, ldst)                                                     \
    __builtin_amdgcn_global_load_lds(                                               \
        (const __attribute__((address_space(1))) uint32_t*)(gsrc),                  \
        (__attribute__((address_space(3))) uint32_t*)(ldst), 16, 0, 0)

// XOR-swizzled byte offset into a [rows][64] bf16 tile (row stride 128 B).
__device__ __forceinline__ uint32_t swz(int row, int col) {
    return (uint32_t)((row * 128 + col * 2) ^ ((row & 7) << 4));
}

// ---------------- pre-pass 1: feats fp32 -> bf16 (+ zero row at index N) ----
__global__ void convert_feats(const float* __restrict__ feats,
                              bf16_t* __restrict__ fb,
                              int n_elems, int total8) {
    int g = blockIdx.x * blockDim.x + threadIdx.x;
    for (; g < total8; g += gridDim.x * blockDim.x) {
        const int e = g * 8;
        bf16x8 v = {};
        if (e < n_elems) {
            f32x4 a = *(const f32x4*)(feats + e);
            f32x4 b = *(const f32x4*)(feats + e + 4);
            #pragma unroll
            for (int i = 0; i < 4; ++i) {
                v[i]     = (bf16_t)a[i];
                v[i + 4] = (bf16_t)b[i];
            }
        }
        *(bf16x8*)(fb + e) = v;
    }
}

// ---------------- pre-pass 2: weight -> transposed + inverse-swizzled bf16 --
// wtb[k] is the 8 KB LDS image as written linearly by global_load_lds: slot
// (dp = t>>3, c' = t&7) holds logical chunk c = c' ^ (dp&7) of Wt[dp][*].
__global__ void convert_weight(const float* __restrict__ w,
                               bf16_t* __restrict__ wtb, int k3) {
    const int k = blockIdx.x;
    const int tid = threadIdx.x;              // 512
    const int dp = tid >> 3;
    const int cp = tid & 7;
    const int d0 = (cp ^ (dp & 7)) * 8;
    const float* src = w + (size_t)k * (D_IN * D_OUT) + (size_t)d0 * D_OUT + dp;
    bf16x8 v;
    #pragma unroll
    for (int j = 0; j < 8; ++j) v[j] = (bf16_t)src[j * D_OUT];
    *(bf16x8*)((char*)wtb + (size_t)k * 8192 + tid * 16) = v;
}

// ---------------- main kernel: triple-buffered, depth-2, counted vmcnt ------
__global__ __launch_bounds__(NTHREADS, 4) void subm_conv_mfma3(
    const bf16_t* __restrict__ fb,      // (N+1) rows x 128 B, row N = zeros
    const int* __restrict__ indices,
    const bf16_t* __restrict__ wtb,     // k3 x 8192 B, pre-swizzled
    float* __restrict__ out,
    int n_vox, int k3)
{
    __shared__ __align__(16) bf16_t As[3][BM * 64];   // 3 x 16 KB
    __shared__ __align__(16) bf16_t Bs[3][64 * 64];   // 3 x  8 KB  (72 KB total)

    const int tid  = threadIdx.x;
    const int lane = tid & 63;
    const int wv   = tid >> 6;
    const int l15  = lane & 15;
    const int l4   = lane >> 4;
    const int wr   = (wv >> 1) * 32;
    const int wc   = (wv & 1) * 32;
    const int n0   = blockIdx.x * BM;

    // A-staging geometry: wave wv stages tile rows [wv*16, wv*16+16).
    const int rA0 = wv * 16 + (lane >> 3);
    const int rA1 = rA0 + 8;
    const int cp  = lane & 7;
    const uint32_t so0 = (uint32_t)((cp ^ (rA0 & 7)) * 16);
    const uint32_t so1 = (uint32_t)((cp ^ (rA1 & 7)) * 16);

    #define LOADIDX(kk, j0, j1) do {                                           \
        const int* ip = indices + (size_t)(kk) * n_vox + n0;                   \
        j0 = (n0 + rA0 < n_vox) ? ip[rA0] : -1;                                \
        j1 = (n0 + rA1 < n_vox) ? ip[rA1] : -1;                                \
    } while (0)

    // 3 loads per stage, issue order B,A,A (uniform count for vmcnt ledger)
    #define STAGE(bufi, kk, j0, j1) do {                                       \
        GLOAD_LDS16((const char*)wtb + (size_t)(kk) * 8192 + tid * 16,         \
                    (char*)&Bs[(bufi)][0] + wv * 1024);                        \
        const size_t r0_ = (size_t)(((j0) >= 0 && (j0) < n_vox) ? (j0) : n_vox); \
        const size_t r1_ = (size_t)(((j1) >= 0 && (j1) < n_vox) ? (j1) : n_vox); \
        GLOAD_LDS16((const char*)fb + r0_ * 128 + so0,                         \
                    (char*)&As[(bufi)][0] + wv * 2048);                        \
        GLOAD_LDS16((const char*)fb + r1_ * 128 + so1,                         \
                    (char*)&As[(bufi)][0] + wv * 2048 + 1024);                 \
    } while (0)

    f32x4 acc[2][2];
    #pragma unroll
    for (int i = 0; i < 2; ++i)
        #pragma unroll
        for (int j = 0; j < 2; ++j)
            acc[i][j] = (f32x4){0.f, 0.f, 0.f, 0.f};

    // ---- prologue: stage tiles 0,1; idx pipeline 2-deep (tiles 2,3) ----
    {
        int p00, p01, p10, p11;
        LOADIDX(0, p00, p01);
        const int k1 = (1 < k3) ? 1 : k3 - 1;
        LOADIDX(k1, p10, p11);
        STAGE(0, 0, p00, p01);
        STAGE(1, k1, p10, p11);
    }
    int ia_c0, ia_c1, ia_n0, ia_n1;
    {
        const int k2 = (2 < k3) ? 2 : k3 - 1;
        const int k3c = (3 < k3) ? 3 : k3 - 1;
        LOADIDX(k2, ia_c0, ia_c1);
        LOADIDX(k3c, ia_n0, ia_n1);
    }

    int bc = 0;   // compute buffer (k % 3)
    int bs = 2;   // stage buffer ((k+2) % 3)

    for (int k = 0; k < k3; ++k) {
        // stage(k) has exactly 5 newer VMEM ops in steady state
        // (idx(k+3):2 + stage(k+1):3) -> counted wait, never drain to 0.
        asm volatile("s_waitcnt vmcnt(5)" ::: "memory");
        __builtin_amdgcn_s_barrier();

        int t0, t1;
        {
            const int ki = (k + 4 < k3) ? k + 4 : k3 - 1;
            LOADIDX(ki, t0, t1);
            const int ks = (k + 2 < k3) ? k + 2 : k3 - 1;
            STAGE(bs, ks, ia_c0, ia_c1);
        }

        const char* ab = (const char*)&As[bc][0];
        const char* bb = (const char*)&Bs[bc][0];
        __builtin_amdgcn_s_setprio(1);
        #pragma unroll
        for (int ks = 0; ks < 2; ++ks) {
            const int kc = ks * 32 + l4 * 8;
            bf16x8 a0 = *(const bf16x8*)(ab + swz(wr + l15,      kc));
            bf16x8 a1 = *(const bf16x8*)(ab + swz(wr + 16 + l15, kc));
            bf16x8 b0 = *(const bf16x8*)(bb + swz(wc + l15,      kc));
            bf16x8 b1 = *(const bf16x8*)(bb + swz(wc + 16 + l15, kc));
            acc[0][0] = __builtin_amdgcn_mfma_f32_16x16x32_bf16(a0, b0, acc[0][0], 0, 0, 0);
            acc[0][1] = __builtin_amdgcn_mfma_f32_16x16x32_bf16(a0, b1, acc[0][1], 0, 0, 0);
            acc[1][0] = __builtin_amdgcn_mfma_f32_16x16x32_bf16(a1, b0, acc[1][0], 0, 0, 0);
            acc[1][1] = __builtin_amdgcn_mfma_f32_16x16x32_bf16(a1, b1, acc[1][1], 0, 0, 0);
        }
        __builtin_amdgcn_s_setprio(0);

        // rotate idx pipeline and buffer counters
        ia_c0 = ia_n0; ia_c1 = ia_n1; ia_n0 = t0; ia_n1 = t1;
        bc = (bc == 2) ? 0 : bc + 1;
        bs = (bs == 2) ? 0 : bs + 1;
    }

    // C/D layout: col = lane&15, row = (lane>>4)*4 + reg
    #pragma unroll
    for (int mi = 0; mi < 2; ++mi)
        #pragma unroll
        for (int ni = 0; ni < 2; ++ni)
            #pragma unroll
            for (int j = 0; j < 4; ++j) {
                const int row = n0 + wr + mi * 16 + l4 * 4 + j;
                const int col = wc + ni * 16 + l15;
                if (row < n_vox)
                    out[(size_t)row * D_OUT + col] = acc[mi][ni][j];
            }
    #undef LOADIDX
    #undef STAGE
}

// ---------------- fallback (round-1 kernel, used if ws too small) ----------
__global__ __launch_bounds__(NTHREADS, 1) void subm_conv_mfma_v1(
    const float* __restrict__ feats,
    const int* __restrict__ indices,
    const float* __restrict__ weight,
    float* __restrict__ out,
    int n_vox, int k3)
{
    __shared__ bf16_t As[BM * 64];
    __shared__ bf16_t Bs[64 * 64];

    const int tid  = threadIdx.x;
    const int lane = tid & 63;
    const int wv   = tid >> 6;
    const int wr   = (wv >> 1) * 32;
    const int wc   = (wv & 1) * 32;
    const int l15  = lane & 15;
    const int l4   = lane >> 4;
    const int n0   = blockIdx.x * BM;

    const int ar = tid >> 2;
    const int ac = (tid & 3) * 16;
    const int bdp = tid & 63;
    const int bd0 = (tid >> 6) * 8;

    f32x4 acc[2][2];
    #pragma unroll
    for (int i = 0; i < 2; ++i)
        #pragma unroll
        for (int j = 0; j < 2; ++j)
            acc[i][j] = (f32x4){0.f, 0.f, 0.f, 0.f};

    for (int k = 0; k < k3; ++k) {
        __syncthreads();
        {
            const int n = n0 + ar;
            int idx = (n < n_vox) ? indices[(size_t)k * n_vox + n] : -1;
            bf16x8 v0 = {}, v1 = {};
            if (idx >= 0) {
                const float* src = feats + (size_t)idx * D_IN + ac;
                f32x4 f0 = *(const f32x4*)(src + 0);
                f32x4 f1 = *(const f32x4*)(src + 4);
                f32x4 f2 = *(const f32x4*)(src + 8);
                f32x4 f3 = *(const f32x4*)(src + 12);
                #pragma unroll
                for (int i = 0; i < 4; ++i) {
                    v0[i]     = (bf16_t)f0[i];
                    v0[i + 4] = (bf16_t)f1[i];
                    v1[i]     = (bf16_t)f2[i];
                    v1[i + 4] = (bf16_t)f3[i];
                }
            }
            *(bf16x8*)((char*)As + swz(ar, ac))     = v0;
            *(bf16x8*)((char*)As + swz(ar, ac + 8)) = v1;
        }
        {
            const float* wsrc = weight + (size_t)k * (D_IN * D_OUT) + (size_t)bd0 * D_OUT + bdp;
            bf16x8 v;
            #pragma unroll
            for (int i = 0; i < 8; ++i) v[i] = (bf16_t)wsrc[i * D_OUT];
            *(bf16x8*)((char*)Bs + swz(bdp, bd0)) = v;
        }
        __syncthreads();
        #pragma unroll
        for (int ks = 0; ks < 2; ++ks) {
            const int kc = ks * 32 + l4 * 8;
            bf16x8 a0 = *(const bf16x8*)((char*)As + swz(wr + l15,      kc));
            bf16x8 a1 = *(const bf16x8*)((char*)As + swz(wr + 16 + l15, kc));
            bf16x8 b0 = *(const bf16x8*)((char*)Bs + swz(wc + l15,      kc));
            bf16x8 b1 = *(const bf16x8*)((char*)Bs + swz(wc + 16 + l15, kc));
            acc[0][0] = __builtin_amdgcn_mfma_f32_16x16x32_bf16(a0, b0, acc[0][0], 0, 0, 0);
            acc[0][1] = __builtin_amdgcn_mfma_f32_16x16x32_bf16(a0, b1, acc[0][1], 0, 0, 0);
            acc[1][0] = __builtin_amdgcn_mfma_f32_16x16x32_bf16(a1, b0, acc[1][0], 0, 0, 0);
            acc[1][1] = __builtin_amdgcn_mfma_f32_16x16x32_bf16(a1, b1, acc[1][1], 0, 0, 0);
        }
    }

    #pragma unroll
    for (int mi = 0; mi < 2; ++mi)
        #pragma unroll
        for (int ni = 0; ni < 2; ++ni)
            #pragma unroll
            for (int j = 0; j < 4; ++j) {
                const int row = n0 + wr + mi * 16 + l4 * 4 + j;
                const int col = wc + ni * 16 + l15;
                if (row < n_vox)
                    out[(size_t)row * D_OUT + col] = acc[mi][ni][j];
            }
}

extern "C" void kernel_launch(void* const* d_in, const int* in_sizes, int n_in,
                              void* d_out, int out_size, void* d_ws, size_t ws_size,
                              hipStream_t stream) {
    const float* feats   = (const float*)d_in[0];
    const int*   indices = (const int*)d_in[1];
    const float* weight  = (const float*)d_in[2];
    float* out = (float*)d_out;

    const int n_vox = in_sizes[0] / D_IN;
    const int k3    = in_sizes[2] / (D_IN * D_OUT);
    const int grid  = (n_vox + BM - 1) / BM;

    const size_t fb_bytes  = (size_t)(n_vox + 1) * D_IN * sizeof(bf16_t);
    const size_t wtb_off   = (fb_bytes + 255) & ~(size_t)255;
    const size_t wtb_bytes = (size_t)k3 * 64 * 64 * sizeof(bf16_t);
    const size_t need      = wtb_off + wtb_bytes;

    if (ws_size >= need && k3 >= 2) {
        bf16_t* fb  = (bf16_t*)((char*)d_ws);
        bf16_t* wtb = (bf16_t*)((char*)d_ws + wtb_off);

        const int n_elems = n_vox * D_IN;
        const int total8  = (n_vox + 1) * (D_IN / 8);
        int cblocks = (total8 + 255) / 256;
        if (cblocks > 2048) cblocks = 2048;
        convert_feats<<<cblocks, 256, 0, stream>>>(feats, fb, n_elems, total8);
        convert_weight<<<k3, 512, 0, stream>>>(weight, wtb, k3);
        subm_conv_mfma3<<<grid, NTHREADS, 0, stream>>>(fb, indices, wtb, out, n_vox, k3);
    } else {
        subm_conv_mfma_v1<<<grid, NTHREADS, 0, stream>>>(feats, indices, weight, out, n_vox, k3);
    }
}